// Round 1
// baseline (333.635 us; speedup 1.0000x reference)
//
#include <hip/hip_runtime.h>

typedef unsigned int u32;
typedef unsigned short u16;
typedef __bf16 bf16x8 __attribute__((ext_vector_type(8)));
typedef float f32x16 __attribute__((ext_vector_type(16)));
typedef u32 u32x4 __attribute__((ext_vector_type(4)));

#define HDIM 128
#define FIN  256
#define NCLS 40
#define NL   4

__device__ __forceinline__ u16 f2b(float f){
  union { __bf16 h; u16 s; } u; u.h = (__bf16)f; return u.s;
}
__device__ __forceinline__ u32 pk(float a, float b){
  union { __bf16 h[2]; u32 w; } u; u.h[0] = (__bf16)a; u.h[1] = (__bf16)b; return u.w;
}
__device__ __forceinline__ float ubf(u32 hbits){
  union { u32 w; float f; } u; u.w = hbits << 16; return u.f;
}

// ---------------- prep: deg/coef + bf16 weights ----------------

__global__ void deg_kernel(const int* __restrict__ ei, float* __restrict__ deg, int E){
  int e = blockIdx.x * 256 + threadIdx.x;
  if(e < E) atomicAdd(&deg[ei[e]], 1.0f);
}

__global__ void coef_kernel(const int* __restrict__ ei, const float* __restrict__ deg,
                            float* __restrict__ coef, int E){
  int e = blockIdx.x * 256 + threadIdx.x;
  if(e < E){
    int r = ei[e], c = ei[E + e];
    float dr = deg[r], dc = deg[c];
    float vr = dr > 0.f ? rsqrtf(dr) : 0.f;
    float vc = dc > 0.f ? rsqrtf(dc) : 0.f;
    atomicAdd(&coef[c], vr * vc);
  }
}

// blocks 0..511: encW convert; 512..1023: W_eff rows; 1024..1151: decW (padded to 64 rows)
__global__ void prep_kernel(const float* __restrict__ encW, const float* __restrict__ Wraw,
                            const float* __restrict__ decW,
                            u16* __restrict__ encB, u16* __restrict__ weffB, u16* __restrict__ decB){
  int b = blockIdx.x, t = threadIdx.x;
  if(b < 512){
    int i = b * 64 + t;                     // 32768 elems
    encB[i] = f2b(encW[i]);
  } else if(b < 1024){
    int idx = b - 512;
    int l = idx >> 7, i = idx & 127;
    const float* Wr = Wraw + (size_t)l * HDIM * (HDIM + 2);
    float w0a, w0b, s = 0.f;
    { int j = t;
      float v = (i < j) ? Wr[i*(HDIM+2)+j] : ((j < i) ? Wr[j*(HDIM+2)+i] : 0.f);
      w0a = v; s += fabsf(v); }
    { int j = t + 64;
      float v = (i < j) ? Wr[i*(HDIM+2)+j] : ((j < i) ? Wr[j*(HDIM+2)+i] : 0.f);
      w0b = v; s += fabsf(v); }
    #pragma unroll
    for(int d = 1; d < 64; d <<= 1) s += __shfl_xor(s, d, 64);
    float diag = Wr[i*(HDIM+2)+HDIM] * s + Wr[i*(HDIM+2)+HDIM+1];
    u16* o = weffB + (size_t)l * HDIM * HDIM + i * HDIM;
    o[t]      = f2b((t == i)      ? diag : w0a);
    o[t + 64] = f2b((t + 64 == i) ? diag : w0b);
  } else {
    int idx = b - 1024;                     // 0..127 -> 8192 elems (64x128)
    int i = idx * 64 + t;
    int c = i >> 7, k = i & 127;
    decB[i] = f2b((c < NCLS) ? decW[c * HDIM + k] : 0.f);
  }
}

// ---------------- fused per-node pipeline ----------------

__device__ __forceinline__ bf16x8 ldsA(const char* sm, int row, int k, int lg){
  int byte = ((row << lg) + (k << 1)) ^ ((row & 7) << 4);
  return *(const bf16x8*)(sm + byte);
}

__device__ __forceinline__ void stage(char* sm, const char* src, int nbytes, int lg){
  for(int off = threadIdx.x * 16; off < nbytes; off += 4096){
    u32x4 v = *(const u32x4*)(src + off);
    int dst = off ^ (((off >> lg) & 7) << 4);
    *(u32x4*)(sm + dst) = v;
  }
}

// Rebuild MFMA B-fragment (col=lane&31 node, k=(lane>>5)*8+j feature) from f32 acc-layout h.
// acc layout: col=lane&31, row(featoff)=(r&3)+8*(r>>2)+4*(lane>>5). One xor-32 hop suffices.
__device__ __forceinline__ bf16x8 buildB(const f32x16& H, int s, int hi){
  const int base = 8 * s;
  u32 P0 = pk(H[base+0], H[base+1]);
  u32 P1 = pk(H[base+2], H[base+3]);
  u32 P2 = pk(H[base+4], H[base+5]);
  u32 P3 = pk(H[base+6], H[base+7]);
  u32 S0 = hi ? P0 : P2;
  u32 S1 = hi ? P1 : P3;
  u32 R0 = __shfl_xor(S0, 32, 64);
  u32 R1 = __shfl_xor(S1, 32, 64);
  union { u32 w[4]; bf16x8 b; } u;
  u.w[0] = hi ? R0 : P0;
  u.w[1] = hi ? R1 : P1;
  u.w[2] = hi ? P2 : R0;
  u.w[3] = hi ? P3 : R1;
  return u.b;
}

__global__ void __launch_bounds__(256, 2)
mega_kernel(const float* __restrict__ x, const float* __restrict__ enc_b,
            const float* __restrict__ W_b, const float* __restrict__ ext_w,
            const float* __restrict__ beta, const float* __restrict__ dec_b,
            const float* __restrict__ coef,
            const u16* __restrict__ encB, const u16* __restrict__ weffB,
            const u16* __restrict__ decB, float* __restrict__ out, int Nn)
{
  __shared__ __align__(16) char smem[65536];
  const int tid  = threadIdx.x;
  const int lane = tid & 63;
  const int wv   = tid >> 6;
  const int hi   = lane >> 5;
  const int ln   = lane & 31;
  const int node = blockIdx.x * 128 + wv * 32 + ln;
  const int nd   = node < Nn ? node : (Nn - 1);
  const float cf = coef[nd];

  // ---- encoder: G = enc_W @ x^T ----
  stage(smem, (const char*)encB, 65536, 9);
  __syncthreads();

  f32x16 h[4];
  #pragma unroll
  for(int nt = 0; nt < 4; nt++)
    #pragma unroll
    for(int i = 0; i < 16; i++) h[nt][i] = 0.f;

  const float* xrow = x + (size_t)nd * FIN;
  #pragma unroll
  for(int ks = 0; ks < 16; ks++){
    const float* xp = xrow + ks * 16 + hi * 8;
    float4 a = *(const float4*)xp;
    float4 b = *(const float4*)(xp + 4);
    union { u32 w[4]; bf16x8 v; } B;
    B.w[0] = pk(a.x, a.y); B.w[1] = pk(a.z, a.w);
    B.w[2] = pk(b.x, b.y); B.w[3] = pk(b.z, b.w);
    #pragma unroll
    for(int nt = 0; nt < 4; nt++){
      bf16x8 A = ldsA(smem, nt * 32 + ln, ks * 16 + hi * 8, 9);
      h[nt] = __builtin_amdgcn_mfma_f32_32x32x16_bf16(A, B.v, h[nt], 0, 0, 0);
    }
  }

  // + enc_b, snapshot h0 (bf16-packed to save VGPRs)
  u32 h0p[4][8];
  #pragma unroll
  for(int nt = 0; nt < 4; nt++){
    #pragma unroll
    for(int q = 0; q < 4; q++){
      float4 eb = *(const float4*)(enc_b + nt * 32 + 8 * q + 4 * hi);
      h[nt][4*q+0] += eb.x; h[nt][4*q+1] += eb.y;
      h[nt][4*q+2] += eb.z; h[nt][4*q+3] += eb.w;
    }
    #pragma unroll
    for(int m = 0; m < 8; m++) h0p[nt][m] = pk(h[nt][2*m], h[nt][2*m+1]);
  }

  // ---- 4 layers ----
  for(int l = 0; l < NL; l++){
    __syncthreads();
    stage(smem, (const char*)weffB + (size_t)l * 32768, 32768, 8);
    __syncthreads();

    f32x16 acc[4];
    #pragma unroll
    for(int nt = 0; nt < 4; nt++)
      #pragma unroll
      for(int i = 0; i < 16; i++) acc[nt][i] = 0.f;

    #pragma unroll
    for(int ks = 0; ks < 8; ks++){
      bf16x8 B = buildB(h[ks >> 1], ks & 1, hi);
      #pragma unroll
      for(int nt = 0; nt < 4; nt++){
        bf16x8 A = ldsA(smem, nt * 32 + ln, ks * 16 + hi * 8, 8);
        acc[nt] = __builtin_amdgcn_mfma_f32_32x32x16_bf16(A, B, acc[nt], 0, 0, 0);
      }
    }

    const float bet = beta[l];
    #pragma unroll
    for(int nt = 0; nt < 4; nt++){
      #pragma unroll
      for(int q = 0; q < 4; q++){
        const int fb = nt * 32 + 8 * q + 4 * hi;
        float4 wb = *(const float4*)(W_b   + l * HDIM + fb);
        float4 ew = *(const float4*)(ext_w + l * HDIM + fb);
        #pragma unroll
        for(int r2 = 0; r2 < 4; r2++){
          const int r = 4 * q + r2;
          float wbv = (r2==0)?wb.x:(r2==1)?wb.y:(r2==2)?wb.z:wb.w;
          float ewv = (r2==0)?ew.x:(r2==1)?ew.y:(r2==2)?ew.z:ew.w;
          u32 w = h0p[nt][r >> 1];
          float h0v = ubf((r & 1) ? (w >> 16) : (w & 0xffffu));
          float o = cf * (acc[nt][r] + wbv) - h[nt][r] * ewv - bet * h0v;
          h[nt][r] += 0.1f * fmaxf(o, 0.f);
        }
      }
    }
  }

  // ---- decoder ----
  __syncthreads();
  stage(smem, (const char*)decB, 16384, 8);
  __syncthreads();

  f32x16 dac[2];
  #pragma unroll
  for(int nt = 0; nt < 2; nt++)
    #pragma unroll
    for(int i = 0; i < 16; i++) dac[nt][i] = 0.f;

  #pragma unroll
  for(int ks = 0; ks < 8; ks++){
    bf16x8 B = buildB(h[ks >> 1], ks & 1, hi);
    #pragma unroll
    for(int nt = 0; nt < 2; nt++){
      bf16x8 A = ldsA(smem, nt * 32 + ln, ks * 16 + hi * 8, 8);
      dac[nt] = __builtin_amdgcn_mfma_f32_32x32x16_bf16(A, B, dac[nt], 0, 0, 0);
    }
  }

  if(node < Nn){
    #pragma unroll
    for(int nt = 0; nt < 2; nt++){
      #pragma unroll
      for(int q = 0; q < 4; q++){
        if(nt == 0 || q == 0){                 // classes < 40 only
          const int c0 = nt * 32 + 8 * q + 4 * hi;
          float4 db = *(const float4*)(dec_b + c0);
          float4 v;
          v.x = dac[nt][4*q+0] + db.x;
          v.y = dac[nt][4*q+1] + db.y;
          v.z = dac[nt][4*q+2] + db.z;
          v.w = dac[nt][4*q+3] + db.w;
          *(float4*)(out + (size_t)node * NCLS + c0) = v;
        }
      }
    }
  }
}

extern "C" void kernel_launch(void* const* d_in, const int* in_sizes, int n_in,
                              void* d_out, int out_size, void* d_ws, size_t ws_size,
                              hipStream_t stream){
  (void)n_in; (void)out_size; (void)ws_size;
  const float* x     = (const float*)d_in[0];
  const int*   ei    = (const int*)  d_in[1];
  const float* encW  = (const float*)d_in[2];
  const float* enc_b = (const float*)d_in[3];
  const float* Wraw  = (const float*)d_in[4];
  const float* W_b   = (const float*)d_in[5];
  const float* ext_w = (const float*)d_in[6];
  const float* beta  = (const float*)d_in[7];
  const float* decW  = (const float*)d_in[8];
  const float* dec_b = (const float*)d_in[9];
  float* out = (float*)d_out;
  const int Nn = in_sizes[0] / FIN;
  const int E  = in_sizes[1] / 2;

  char* ws = (char*)d_ws;
  size_t szN = ((size_t)Nn * 4 + 511) & ~(size_t)511;
  float* deg  = (float*)(ws);
  float* coef = (float*)(ws + szN);
  u16* encB  = (u16*)(ws + 2 * szN);
  u16* weffB = (u16*)(ws + 2 * szN + 65536);
  u16* decB  = (u16*)(ws + 2 * szN + 65536 + 131072);

  hipMemsetAsync(ws, 0, 2 * szN, stream);
  prep_kernel<<<1152, 64, 0, stream>>>(encW, Wraw, decW, encB, weffB, decB);
  deg_kernel <<<(E + 255) / 256, 256, 0, stream>>>(ei, deg, E);
  coef_kernel<<<(E + 255) / 256, 256, 0, stream>>>(ei, deg, coef, E);
  mega_kernel<<<(Nn + 127) / 128, 256, 0, stream>>>(x, enc_b, W_b, ext_w, beta, dec_b,
                                                    coef, encB, weffB, decB, out, Nn);
}